// Round 6
// baseline (104.126 us; speedup 1.0000x reference)
//
#include <hip/hip_runtime.h>

// Problem constants
#define N_FILTERS 1024
#define B_TOTAL   1024
#define IMG       64            // H = W = 64
#define PAD_DIM   70            // 64 + 2*3 padded image side
// Xt layout in d_ws: fp16 [4900 pixels][1024 batches] (10 MB).
// bg = blockIdx&3 -> round-robin XCD dispatch pins a 256-batch slice per XCD:
// 4900 px * 512 B = 2.5 MB hot set, fits the 4 MB per-XCD L2.
// Window consumed per filter: padded rows i..i+9, cols j..j+9 (pool floor mode
// discards conv row/col 6 -> only a 10x10 slab of the 11x11 window is read).

typedef _Float16 half2_t __attribute__((ext_vector_type(2)));
typedef float    fvec2   __attribute__((ext_vector_type(2)));

// ---------------- prep: transpose X [1024 b][4096 px] -> Xt fp16 [px][b], + border zero ----
// blocks 0..511: transpose tile (64 px x 128 b). blocks 512..575: zero padded border.
__global__ __launch_bounds__(256) void prep_kernel(
    const float* __restrict__ X, _Float16* __restrict__ Xt)
{
    if (blockIdx.x < 512) {
        __shared__ float T[128 * 65];        // [b_local][px_local], stride 65
        const int pt = blockIdx.x & 63;      // pixel tile (64 pixels)
        const int bt = blockIdx.x >> 6;      // batch tile (128 batches)
        const int tx = threadIdx.x & 63, ty = threadIdx.x >> 6;

        #pragma unroll
        for (int pass = 0; pass < 32; ++pass) {
            int bl = pass * 4 + ty;          // lanes: consecutive pixels -> 256 B coalesced
            T[bl * 65 + tx] = X[(size_t)(bt * 128 + bl) * 4096 + pt * 64 + tx];
        }
        __syncthreads();
        #pragma unroll
        for (int pass = 0; pass < 16; ++pass) {
            int pl = pass * 4 + ty;          // pixel within tile
            int p  = pt * 64 + pl;
            int r  = p >> 6, c = p & 63;
            // lane tx packs batches (2tx, 2tx+1) -> one dword store, 256 B/wave
            half2_t h;
            h.x = (_Float16)T[(2 * tx) * 65 + pl];      // 4-way LDS bank alias: ~1.6x, ok
            h.y = (_Float16)T[(2 * tx + 1) * 65 + pl];
            *(half2_t*)&Xt[(size_t)((r + 3) * PAD_DIM + (c + 3)) * 1024 + bt * 128 + 2 * tx] = h;
        }
    } else {
        // border zeroing: 804 border pixels x 2048 B
        const int bp = blockIdx.x - 512;     // 0..63
        for (int pp = bp; pp < PAD_DIM * PAD_DIM; pp += 64) {
            int r = pp / PAD_DIM, c = pp - r * PAD_DIM;
            if (r >= 3 && r < 67 && c >= 3 && c < 67) continue;
            unsigned int* q = (unsigned int*)Xt + (size_t)pp * 512;
            q[threadIdx.x] = 0u;
            q[threadIdx.x + 256] = 0u;
        }
    }
}

// ---------------- main: lanes = batch (4/lane), wave = one filter ----------------
// Block = 4 waves -> filters fg*4..fg*4+3 (completes 64 B out lines), batches
// bg*256..bg*256+255 (4/lane via one dwordx2 = 4 fp16). Filter metadata scalar.
__global__ __launch_bounds__(256, 2) void filters_main(
    const _Float16* __restrict__ Xt,   // [4900 px][1024 b] fp16
    const float*    __restrict__ W,    // [F][25]
    const float*    __restrict__ bias, // [F]
    const int*      __restrict__ pos,  // [F][2]
    float4*         __restrict__ out4) // [B][1024 float4] (= [B][F*4] floats)
{
    const int t    = threadIdx.x;
    const int lane = t & 63;
    const int w    = t >> 6;                       // wave id 0..3
    const int bg   = blockIdx.x & 3;               // batch group (256 batches) -> XCD pin
    const int fg   = blockIdx.x >> 2;              // filter group (4 filters)

    const int f  = fg * 4 + w;
    const int sf = __builtin_amdgcn_readfirstlane(f);
    const int si = __builtin_amdgcn_readfirstlane(pos[2 * sf]);       // row i, 0..59
    const int sj = __builtin_amdgcn_readfirstlane(pos[2 * sf + 1]);   // col j, 0..59

    float wk[25];
    const float* wp = W + sf * 25;                 // scalar address -> s_load into SGPRs
    #pragma unroll
    for (int k = 0; k < 25; ++k) wk[k] = wp[k];

    // per-lane byte offset within a pixel's 2048 B batch row
    const int laneByte = bg * 512 + lane * 8;      // 4 batches (8 B) per lane

    fvec2 a0[36], a1[36];                          // batches (4l,4l+1) and (4l+2,4l+3)
    #pragma unroll
    for (int k = 0; k < 36; ++k) { a0[k] = (fvec2)0.0f; a1[k] = (fvec2)0.0f; }

    #pragma unroll
    for (int wr = 0; wr < 10; ++wr) {
        const char* rowp = (const char*)Xt
                         + (size_t)((si + wr) * PAD_DIM + sj) * 2048 + laneByte;
        fvec2 inA[10], inB[10];
        #pragma unroll
        for (int wc = 0; wc < 10; ++wc) {
            // pixel stride = 2048 B; one dwordx2 per px = 4 fp16 batches, 512 B/wave
            half2_t lo, hi;
            uint2 d = *(const uint2*)(rowp + (size_t)wc * 2048);
            lo = __builtin_bit_cast(half2_t, d.x);
            hi = __builtin_bit_cast(half2_t, d.y);
            inA[wc].x = (float)lo.x; inA[wc].y = (float)lo.y;
            inB[wc].x = (float)hi.x; inB[wc].y = (float)hi.y;
        }
        // conv row y uses window rows y..y+4  =>  y in [max(0,wr-4), min(5,wr)]
        #pragma unroll
        for (int y = 0; y < 6; ++y) {
            if (y >= ((wr > 4) ? (wr - 4) : 0) && y <= ((wr < 5) ? wr : 5)) {
                const int r = wr - y;
                #pragma unroll
                for (int x = 0; x < 6; ++x) {
                    #pragma unroll
                    for (int c = 0; c < 5; ++c) {
                        a0[y * 6 + x] = wk[r * 5 + c] * inA[x + c] + a0[y * 6 + x];
                        a1[y * 6 + x] = wk[r * 5 + c] * inB[x + c] + a1[y * 6 + x];
                    }
                }
            }
        }
    }

    // 3x3 maxpool (stride 3) over the 6x6 conv grid -> 2x2; bias after max
    const float bv = bias[sf];
    float4 o0, o1;
    {
        fvec2 m0[4], m1[4];
        #pragma unroll
        for (int py = 0; py < 2; ++py) {
            #pragma unroll
            for (int px = 0; px < 2; ++px) {
                fvec2 u = a0[(3 * py) * 6 + 3 * px];
                fvec2 v = a1[(3 * py) * 6 + 3 * px];
                #pragma unroll
                for (int dy = 0; dy < 3; ++dy)
                    #pragma unroll
                    for (int dx = 0; dx < 3; ++dx) {
                        fvec2 e0 = a0[(3 * py + dy) * 6 + (3 * px + dx)];
                        fvec2 e1 = a1[(3 * py + dy) * 6 + (3 * px + dx)];
                        u.x = fmaxf(u.x, e0.x); u.y = fmaxf(u.y, e0.y);
                        v.x = fmaxf(v.x, e1.x); v.y = fmaxf(v.y, e1.y);
                    }
                m0[py * 2 + px].x = u.x + bv; m0[py * 2 + px].y = u.y + bv;
                m1[py * 2 + px].x = v.x + bv; m1[py * 2 + px].y = v.y + bv;
            }
        }
        // batch 4l+0: m0.x of each; 4l+1: m0.y; 4l+2: m1.x; 4l+3: m1.y
        const int b0 = bg * 256 + lane * 4;
        float4 o;
        o.x = m0[0].x; o.y = m0[1].x; o.z = m0[2].x; o.w = m0[3].x;
        out4[(size_t)b0 * 1024 + f] = o;
        o.x = m0[0].y; o.y = m0[1].y; o.z = m0[2].y; o.w = m0[3].y;
        out4[(size_t)(b0 + 1) * 1024 + f] = o;
        o.x = m1[0].x; o.y = m1[1].x; o.z = m1[2].x; o.w = m1[3].x;
        out4[(size_t)(b0 + 2) * 1024 + f] = o;
        o.x = m1[0].y; o.y = m1[1].y; o.z = m1[2].y; o.w = m1[3].y;
        out4[(size_t)(b0 + 3) * 1024 + f] = o;
        (void)o0; (void)o1;
    }
}

extern "C" void kernel_launch(void* const* d_in, const int* in_sizes, int n_in,
                              void* d_out, int out_size, void* d_ws, size_t ws_size,
                              hipStream_t stream) {
    const float* X    = (const float*)d_in[0];
    const float* W    = (const float*)d_in[1];
    const float* bias = (const float*)d_in[2];
    const int*   pos  = (const int*)d_in[3];
    float4* out4 = (float4*)d_out;
    _Float16* Xt = (_Float16*)d_ws;        // 70*70*1024 fp16 = 10 MB

    prep_kernel<<<576, 256, 0, stream>>>(X, Xt);
    filters_main<<<1024, 256, 0, stream>>>(Xt, W, bias, pos, out4);
}